// Round 6
// baseline (112.616 us; speedup 1.0000x reference)
//
#include <hip/hip_runtime.h>
#include <hip/hip_bf16.h>

#define NB 8
#define NC 128
#define NH 48
#define NW 64
#define NS 3072  // NH*NW
#define EPSF 1e-6f

#define GLOBAL_AS __attribute__((address_space(1)))
#define LDS_AS __attribute__((address_space(3)))

typedef __bf16 bf16x8 __attribute__((ext_vector_type(8)));
typedef float f32x4 __attribute__((ext_vector_type(4)));

// ---------------------------------------------------------------------------
// Fused transpose+convert for BOTH inputs: f32 [B][C][S] -> bf16 [B][S][C].
// 1D grid, b = id&7 pins batch to XCD.
// ---------------------------------------------------------------------------
__global__ __launch_bounds__(256) void transpose_both(
    const float* __restrict__ x, const float* __restrict__ y,
    __hip_bfloat16* __restrict__ AT, __hip_bfloat16* __restrict__ BT) {
  __shared__ float tile[32][65];
  const int id = blockIdx.x;
  const int b = id & 7;
  const int which = (id >> 3) & 1;
  const int rr = id >> 4;  // 0..191
  const int f0 = (rr % 96) * 32, c0 = (rr / 96) * 64;
  const float* src = which ? y : x;
  __hip_bfloat16* dst = which ? BT : AT;
  const int t = threadIdx.x;

  const int fi = t & 31, ci0 = t >> 5;
  const float* sp = src + ((size_t)b * NC + c0) * NS + f0;
#pragma unroll
  for (int i = 0; i < 8; ++i) {
    int ci = ci0 + i * 8;
    tile[fi][ci] = sp[(size_t)ci * NS + fi];
  }
  __syncthreads();

  const int co = t & 63, fo0 = t >> 6;
#pragma unroll
  for (int i = 0; i < 8; ++i) {
    int fo = fo0 + i * 4;
    int f = f0 + fo;
    int k = which ? f : ((f & 63) * NH + (f >> 6));  // x: k = v*H + u
    dst[((size_t)b * NS + k) * NC + c0 + co] = __float2bfloat16(tile[fo][co]);
  }
}

// ---------------------------------------------------------------------------
// GEMM: T[m][n] = sum_c AT[b][mt*128+m][c] * BT[b][nt*128+n][c], K=C=128.
// 1D grid (4608); b = id&7 pins batch to XCD.
// Staging: global_load_lds width=16, linear LDS dest, inverse-swizzled global
// source; read side uses g ^ (row&7) (layout identical to verified round-1).
// WRITE=false: part_out[mt][b][n] = sum_m relu(T)^2
// WRITE=true : out[b][m][n] = relu(T) * rsqrt(sum_mt part_in + eps).
//   Epilogue repacks the 128x128 f32 tile through LDS ([128][129] pad), then
//   stores dwordx4 full-line PLAIN stores (L2-aggregated; this round's single
//   change: nontemporal dropped to let L2 cluster the 512 B row-chunks into
//   page-friendly eviction bursts).
// ---------------------------------------------------------------------------
template <bool WRITE>
__global__ __launch_bounds__(256, 2) void corr_gemm(
    const __hip_bfloat16* __restrict__ AT,
    const __hip_bfloat16* __restrict__ BT,
    const float* __restrict__ part_in, float* __restrict__ part_out,
    float* __restrict__ out) {
  __shared__ char smem[66560];  // 64 KB tiles (A,B) + 512 B rn; epilogue
                                // reuses first 66048 B as f32 [128][129]
  float* rnc = (float*)(smem + 65536);
  const int id = blockIdx.x;
  const int b = id & 7;
  const int tl = id >> 3;
  const int mt = tl / 24, nt = tl - mt * 24;
  const int t = threadIdx.x;
  const int lane = t & 63, wid = t >> 6;
  const int wm = wid >> 1, wn = wid & 1;
  const int l15 = lane & 15, kg = lane >> 4;

  // ---- async stage both 32 KB tiles ----
  const char* Ag = (const char*)(AT + ((size_t)b * NS + mt * 128) * NC);
  const char* Bg = (const char*)(BT + ((size_t)b * NS + nt * 128) * NC);
  {
    const int lr = lane >> 4, lg = lane & 15;
#pragma unroll
    for (int i = 0; i < 8; ++i) {
      int c = wid * 8 + i;        // 1 KB chunk index 0..31
      int row = c * 4 + lr;       // LDS row this lane lands in
      int g = lg ^ (row & 7);     // inverse swizzle on the SOURCE granule
      int go = row * 256 + g * 16;
      __builtin_amdgcn_global_load_lds((const GLOBAL_AS unsigned*)(Ag + go),
                                       (LDS_AS unsigned*)(smem + c * 1024),
                                       16, 0, 0);
      __builtin_amdgcn_global_load_lds(
          (const GLOBAL_AS unsigned*)(Bg + go),
          (LDS_AS unsigned*)(smem + 32768 + c * 1024), 16, 0, 0);
    }
  }
  if (WRITE) {
    // fused norm: rn for this block's 128 columns (overlaps with staging)
    if (t < 128) {
      float s = 0.f;
#pragma unroll
      for (int q = 0; q < 24; ++q)
        s += part_in[(size_t)q * (NB * NS) + (size_t)b * NS + nt * 128 + t];
      rnc[t] = rsqrtf(s + EPSF);
    }
  }
  __syncthreads();  // drains vmcnt (global_load_lds) + lgkm (rnc)

  // ---- MFMA main: 4 K-steps of 32, 16 MFMA each ----
  f32x4 acc[4][4] = {};
  const int rx = l15 & 7;
#pragma unroll
  for (int kk = 0; kk < 4; ++kk) {
    int g = (kk * 4 + kg) ^ rx;  // swizzled granule within row
    bf16x8 a[4], bb[4];
#pragma unroll
    for (int mi = 0; mi < 4; ++mi) {
      int row = wm * 64 + mi * 16 + l15;
      a[mi] = *(const bf16x8*)(smem + row * 256 + g * 16);
    }
#pragma unroll
    for (int ni = 0; ni < 4; ++ni) {
      int row = wn * 64 + ni * 16 + l15;
      bb[ni] = *(const bf16x8*)(smem + 32768 + row * 256 + g * 16);
    }
#pragma unroll
    for (int mi = 0; mi < 4; ++mi)
#pragma unroll
      for (int ni = 0; ni < 4; ++ni)
        acc[mi][ni] = __builtin_amdgcn_mfma_f32_16x16x32_bf16(
            a[mi], bb[ni], acc[mi][ni], 0, 0, 0);
  }

  if (!WRITE) {
    // per-column (n) sum of relu^2 over this tile's 128 rows
    float cs[4] = {0.f, 0.f, 0.f, 0.f};
#pragma unroll
    for (int ni = 0; ni < 4; ++ni)
#pragma unroll
      for (int mi = 0; mi < 4; ++mi)
#pragma unroll
        for (int r = 0; r < 4; ++r) {
          float v = fmaxf(acc[mi][ni][r], 0.f);
          cs[ni] += v * v;
        }
#pragma unroll
    for (int ni = 0; ni < 4; ++ni) {
      cs[ni] += __shfl_xor(cs[ni], 16, 64);
      cs[ni] += __shfl_xor(cs[ni], 32, 64);
    }
    __syncthreads();  // all waves done reading tiles; reuse LDS
    float* csum = (float*)smem;  // [2][128]
    if (kg == 0) {
#pragma unroll
      for (int ni = 0; ni < 4; ++ni)
        csum[wm * 128 + wn * 64 + ni * 16 + l15] = cs[ni];
    }
    __syncthreads();
    if (t < 128) {
      float s = csum[t] + csum[128 + t];
      part_out[(size_t)mt * (NB * NS) + (size_t)b * NS + nt * 128 + t] = s;
    }
  } else {
    // grab rn before LDS is repurposed
    float rnv[4];
#pragma unroll
    for (int ni = 0; ni < 4; ++ni) rnv[ni] = rnc[wn * 64 + ni * 16 + l15];
    __syncthreads();  // tiles + rnc fully consumed

    // repack scaled tile into f32 [128][129] (pad: worst-case small aliasing)
    float* tf = (float*)smem;
#pragma unroll
    for (int mi = 0; mi < 4; ++mi)
#pragma unroll
      for (int ni = 0; ni < 4; ++ni)
#pragma unroll
        for (int r = 0; r < 4; ++r) {
          int row = wm * 64 + mi * 16 + kg * 4 + r;
          int col = wn * 64 + ni * 16 + l15;
          tf[row * 129 + col] = fmaxf(acc[mi][ni][r], 0.f) * rnv[ni];
        }
    __syncthreads();

    // stream out: 2 full rows x 512 B per wave instruction (all-full lines)
    float* ob = out + (size_t)b * NS * NS + (size_t)(mt * 128) * NS + nt * 128;
    const int rsub = t >> 5, c4 = (t & 31) * 4;
#pragma unroll
    for (int it = 0; it < 16; ++it) {
      int row = it * 8 + rsub;
      f32x4 v = *(const f32x4*)&tf[row * 129 + c4];
      *(f32x4*)&ob[(size_t)row * NS + c4] = v;  // plain store (A/B: no nt)
    }
  }
}

extern "C" void kernel_launch(void* const* d_in, const int* in_sizes, int n_in,
                              void* d_out, int out_size, void* d_ws,
                              size_t ws_size, hipStream_t stream) {
  const float* x = (const float*)d_in[0];
  const float* y = (const float*)d_in[1];
  float* out = (float*)d_out;
  char* ws = (char*)d_ws;

  const size_t AT_OFF = 0;           // 8*3072*128*2 = 6,291,456
  const size_t BT_OFF = 6291456;     // + 6,291,456
  const size_t PART_OFF = 12582912;  // 24*24576*4 = 2,359,296
  const size_t NEED = 14942208;
  if (ws_size < NEED) return;

  __hip_bfloat16* AT = (__hip_bfloat16*)(ws + AT_OFF);
  __hip_bfloat16* BT = (__hip_bfloat16*)(ws + BT_OFF);
  float* part = (float*)(ws + PART_OFF);

  dim3 tb(256);
  transpose_both<<<dim3(3072), tb, 0, stream>>>(x, y, AT, BT);
  corr_gemm<false><<<dim3(4608), tb, 0, stream>>>(AT, BT, nullptr, part,
                                                  nullptr);
  corr_gemm<true><<<dim3(4608), tb, 0, stream>>>(AT, BT, part, nullptr, out);
}

// Round 7
// 101.636 us; speedup vs baseline: 1.1080x; 1.1080x over previous
//
#include <hip/hip_runtime.h>
#include <hip/hip_bf16.h>

#define NB 8
#define NC 128
#define NH 48
#define NW 64
#define NS 3072  // NH*NW
#define EPSF 1e-6f

#define GLOBAL_AS __attribute__((address_space(1)))
#define LDS_AS __attribute__((address_space(3)))

typedef __bf16 bf16x8 __attribute__((ext_vector_type(8)));
typedef float f32x4 __attribute__((ext_vector_type(4)));

// ---------------------------------------------------------------------------
// Fused transpose+convert for BOTH inputs: f32 [B][C][S] -> bf16 [B][S][C].
// (unchanged from round 3)
// ---------------------------------------------------------------------------
__global__ __launch_bounds__(256) void transpose_both(
    const float* __restrict__ x, const float* __restrict__ y,
    __hip_bfloat16* __restrict__ AT, __hip_bfloat16* __restrict__ BT) {
  __shared__ float tile[32][65];
  const int id = blockIdx.x;
  const int b = id & 7;
  const int which = (id >> 3) & 1;
  const int rr = id >> 4;  // 0..191
  const int f0 = (rr % 96) * 32, c0 = (rr / 96) * 64;
  const float* src = which ? y : x;
  __hip_bfloat16* dst = which ? BT : AT;
  const int t = threadIdx.x;

  const int fi = t & 31, ci0 = t >> 5;
  const float* sp = src + ((size_t)b * NC + c0) * NS + f0;
#pragma unroll
  for (int i = 0; i < 8; ++i) {
    int ci = ci0 + i * 8;
    tile[fi][ci] = sp[(size_t)ci * NS + fi];
  }
  __syncthreads();

  const int co = t & 63, fo0 = t >> 6;
#pragma unroll
  for (int i = 0; i < 8; ++i) {
    int fo = fo0 + i * 4;
    int f = f0 + fo;
    int k = which ? f : ((f & 63) * NH + (f >> 6));  // x: k = v*H + u
    dst[((size_t)b * NS + k) * NC + c0 + co] = __float2bfloat16(tile[fo][co]);
  }
}

// ---------------------------------------------------------------------------
// Pass 1 (unchanged round-3 verified kernel): 128x128 tile, 256 threads,
// part_out[mt][b][n] = sum_m relu(T)^2.
// ---------------------------------------------------------------------------
__global__ __launch_bounds__(256, 2) void corr_part(
    const __hip_bfloat16* __restrict__ AT,
    const __hip_bfloat16* __restrict__ BT, float* __restrict__ part_out) {
  __shared__ char smem[65536];
  const int id = blockIdx.x;
  const int b = id & 7;
  const int tl = id >> 3;
  const int mt = tl / 24, nt = tl - mt * 24;
  const int t = threadIdx.x;
  const int lane = t & 63, wid = t >> 6;
  const int wm = wid >> 1, wn = wid & 1;
  const int l15 = lane & 15, kg = lane >> 4;

  const char* Ag = (const char*)(AT + ((size_t)b * NS + mt * 128) * NC);
  const char* Bg = (const char*)(BT + ((size_t)b * NS + nt * 128) * NC);
  {
    const int lr = lane >> 4, lg = lane & 15;
#pragma unroll
    for (int i = 0; i < 8; ++i) {
      int c = wid * 8 + i;
      int row = c * 4 + lr;
      int g = lg ^ (row & 7);
      int go = row * 256 + g * 16;
      __builtin_amdgcn_global_load_lds((const GLOBAL_AS unsigned*)(Ag + go),
                                       (LDS_AS unsigned*)(smem + c * 1024),
                                       16, 0, 0);
      __builtin_amdgcn_global_load_lds(
          (const GLOBAL_AS unsigned*)(Bg + go),
          (LDS_AS unsigned*)(smem + 32768 + c * 1024), 16, 0, 0);
    }
  }
  __syncthreads();

  f32x4 acc[4][4] = {};
  const int rx = l15 & 7;
#pragma unroll
  for (int kk = 0; kk < 4; ++kk) {
    int g = (kk * 4 + kg) ^ rx;
    bf16x8 a[4], bb[4];
#pragma unroll
    for (int mi = 0; mi < 4; ++mi)
      a[mi] = *(const bf16x8*)(smem + (wm * 64 + mi * 16 + l15) * 256 + g * 16);
#pragma unroll
    for (int ni = 0; ni < 4; ++ni)
      bb[ni] = *(const bf16x8*)(smem + 32768 +
                                (wn * 64 + ni * 16 + l15) * 256 + g * 16);
#pragma unroll
    for (int mi = 0; mi < 4; ++mi)
#pragma unroll
      for (int ni = 0; ni < 4; ++ni)
        acc[mi][ni] = __builtin_amdgcn_mfma_f32_16x16x32_bf16(
            a[mi], bb[ni], acc[mi][ni], 0, 0, 0);
  }

  float cs[4] = {0.f, 0.f, 0.f, 0.f};
#pragma unroll
  for (int ni = 0; ni < 4; ++ni)
#pragma unroll
    for (int mi = 0; mi < 4; ++mi)
#pragma unroll
      for (int r = 0; r < 4; ++r) {
        float v = fmaxf(acc[mi][ni][r], 0.f);
        cs[ni] += v * v;
      }
#pragma unroll
  for (int ni = 0; ni < 4; ++ni) {
    cs[ni] += __shfl_xor(cs[ni], 16, 64);
    cs[ni] += __shfl_xor(cs[ni], 32, 64);
  }
  __syncthreads();
  float* csum = (float*)smem;  // [2][128]
  if (kg == 0) {
#pragma unroll
    for (int ni = 0; ni < 4; ++ni)
      csum[wm * 128 + wn * 64 + ni * 16 + l15] = cs[ni];
  }
  __syncthreads();
  if (t < 128) {
    float s = csum[t] + csum[128 + t];
    part_out[(size_t)mt * (NB * NS) + (size_t)b * NS + nt * 128 + t] = s;
  }
}

// ---------------------------------------------------------------------------
// Pass 2: 128(m) x 256(n) tile, 512 threads (8 waves as 2x4 of 64x64).
// LDS: A 32K | B 64K | rn 1K = 99,328 B -> 1 block/CU, 2 waves/SIMD.
// Staging/swizzle/fragment math identical to verified round-1/3 pattern.
// Epilogue: repack 64 rows at a time into f32 [64][258], then nt-store
// 1 KB per wave-instruction = one FULL output row (monotonic run).
// ---------------------------------------------------------------------------
__global__ __launch_bounds__(512, 2) void corr_out256(
    const __hip_bfloat16* __restrict__ AT,
    const __hip_bfloat16* __restrict__ BT, const float* __restrict__ part_in,
    float* __restrict__ out) {
  __shared__ char smem[99328];  // A 32K | B 64K | rn 1K
  float* rnc = (float*)(smem + 98304);
  const int id = blockIdx.x;
  const int b = id & 7;
  const int tl = id >> 3;  // 0..287
  const int mt = tl / 12, nt = tl - mt * 12;
  const int t = threadIdx.x;  // 0..511
  const int lane = t & 63, wid = t >> 6;  // 8 waves
  const int wm = wid >> 2, wn = wid & 3;  // 2 x 4
  const int l15 = lane & 15, kg = lane >> 4;

  const char* Ag = (const char*)(AT + ((size_t)b * NS + mt * 128) * NC);
  const char* Bg = (const char*)(BT + ((size_t)b * NS + nt * 256) * NC);
  {
    const int lr = lane >> 4, lg = lane & 15;
#pragma unroll
    for (int i = 0; i < 4; ++i) {  // A: 32 chunks of 1 KB
      int c = wid * 4 + i;
      int row = c * 4 + lr;
      int g = lg ^ (row & 7);
      __builtin_amdgcn_global_load_lds(
          (const GLOBAL_AS unsigned*)(Ag + row * 256 + g * 16),
          (LDS_AS unsigned*)(smem + c * 1024), 16, 0, 0);
    }
#pragma unroll
    for (int i = 0; i < 8; ++i) {  // B: 64 chunks of 1 KB
      int c = wid * 8 + i;
      int row = c * 4 + lr;
      int g = lg ^ (row & 7);
      __builtin_amdgcn_global_load_lds(
          (const GLOBAL_AS unsigned*)(Bg + row * 256 + g * 16),
          (LDS_AS unsigned*)(smem + 32768 + c * 1024), 16, 0, 0);
    }
  }
  // fused norm for this block's 256 columns (overlaps staging)
  if (t < 256) {
    float s = 0.f;
#pragma unroll
    for (int q = 0; q < 24; ++q)
      s += part_in[(size_t)q * (NB * NS) + (size_t)b * NS + nt * 256 + t];
    rnc[t] = rsqrtf(s + EPSF);
  }
  __syncthreads();

  f32x4 acc[4][4] = {};
  const int rx = l15 & 7;
#pragma unroll
  for (int kk = 0; kk < 4; ++kk) {
    int g = (kk * 4 + kg) ^ rx;
    bf16x8 a[4], bb[4];
#pragma unroll
    for (int mi = 0; mi < 4; ++mi)
      a[mi] = *(const bf16x8*)(smem + (wm * 64 + mi * 16 + l15) * 256 + g * 16);
#pragma unroll
    for (int ni = 0; ni < 4; ++ni)
      bb[ni] = *(const bf16x8*)(smem + 32768 +
                                (wn * 64 + ni * 16 + l15) * 256 + g * 16);
#pragma unroll
    for (int mi = 0; mi < 4; ++mi)
#pragma unroll
      for (int ni = 0; ni < 4; ++ni)
        acc[mi][ni] = __builtin_amdgcn_mfma_f32_16x16x32_bf16(
            a[mi], bb[ni], acc[mi][ni], 0, 0, 0);
  }

  float rnv[4];
#pragma unroll
  for (int ni = 0; ni < 4; ++ni) rnv[ni] = rnc[wn * 64 + ni * 16 + l15];
  __syncthreads();  // tiles + rnc fully consumed; LDS reused below

  float* tf = (float*)smem;  // [64][258] per chunk = 66,048 B
  float* ob = out + (size_t)b * NS * NS + (size_t)(mt * 128) * NS + nt * 256;
#pragma unroll
  for (int ch = 0; ch < 2; ++ch) {
    if (wm == ch) {  // waves owning rows [ch*64, ch*64+64) repack
#pragma unroll
      for (int mi = 0; mi < 4; ++mi)
#pragma unroll
        for (int ni = 0; ni < 4; ++ni)
#pragma unroll
          for (int r = 0; r < 4; ++r) {
            int row = mi * 16 + kg * 4 + r;          // 0..63 local
            int col = wn * 64 + ni * 16 + l15;       // 0..255
            tf[row * 258 + col] = fmaxf(acc[mi][ni][r], 0.f) * rnv[ni];
          }
    }
    __syncthreads();
    // store 64 rows; one wave instruction = one full 1 KB row (monotonic)
#pragma unroll
    for (int it = 0; it < 8; ++it) {
      int rl = wid + it * 8;  // 0..63
      f32x4 v = *(const f32x4*)&tf[rl * 258 + lane * 4];
      __builtin_nontemporal_store(
          v, (f32x4*)&ob[(size_t)(ch * 64 + rl) * NS + lane * 4]);
    }
    __syncthreads();
  }
}

extern "C" void kernel_launch(void* const* d_in, const int* in_sizes, int n_in,
                              void* d_out, int out_size, void* d_ws,
                              size_t ws_size, hipStream_t stream) {
  const float* x = (const float*)d_in[0];
  const float* y = (const float*)d_in[1];
  float* out = (float*)d_out;
  char* ws = (char*)d_ws;

  const size_t AT_OFF = 0;           // 8*3072*128*2 = 6,291,456
  const size_t BT_OFF = 6291456;     // + 6,291,456
  const size_t PART_OFF = 12582912;  // 24*24576*4 = 2,359,296
  const size_t NEED = 14942208;
  if (ws_size < NEED) return;

  __hip_bfloat16* AT = (__hip_bfloat16*)(ws + AT_OFF);
  __hip_bfloat16* BT = (__hip_bfloat16*)(ws + BT_OFF);
  float* part = (float*)(ws + PART_OFF);

  transpose_both<<<dim3(3072), dim3(256), 0, stream>>>(x, y, AT, BT);
  corr_part<<<dim3(4608), dim3(256), 0, stream>>>(AT, BT, part);
  corr_out256<<<dim3(2304), dim3(512), 0, stream>>>(AT, BT, part, out);
}

// Round 8
// 99.189 us; speedup vs baseline: 1.1354x; 1.0247x over previous
//
#include <hip/hip_runtime.h>
#include <hip/hip_bf16.h>

#define NB 8
#define NC 128
#define NH 48
#define NW 64
#define NS 3072  // NH*NW
#define EPSF 1e-6f

#define GLOBAL_AS __attribute__((address_space(1)))
#define LDS_AS __attribute__((address_space(3)))

typedef __bf16 bf16x8 __attribute__((ext_vector_type(8)));
typedef float f32x4 __attribute__((ext_vector_type(4)));

// ---------------------------------------------------------------------------
// Fused transpose+convert for BOTH inputs: f32 [B][C][S] -> bf16 [B][S][C].
// (unchanged, verified since round 3)
// ---------------------------------------------------------------------------
__global__ __launch_bounds__(256) void transpose_both(
    const float* __restrict__ x, const float* __restrict__ y,
    __hip_bfloat16* __restrict__ AT, __hip_bfloat16* __restrict__ BT) {
  __shared__ float tile[32][65];
  const int id = blockIdx.x;
  const int b = id & 7;
  const int which = (id >> 3) & 1;
  const int rr = id >> 4;  // 0..191
  const int f0 = (rr % 96) * 32, c0 = (rr / 96) * 64;
  const float* src = which ? y : x;
  __hip_bfloat16* dst = which ? BT : AT;
  const int t = threadIdx.x;

  const int fi = t & 31, ci0 = t >> 5;
  const float* sp = src + ((size_t)b * NC + c0) * NS + f0;
#pragma unroll
  for (int i = 0; i < 8; ++i) {
    int ci = ci0 + i * 8;
    tile[fi][ci] = sp[(size_t)ci * NS + fi];
  }
  __syncthreads();

  const int co = t & 63, fo0 = t >> 6;
#pragma unroll
  for (int i = 0; i < 8; ++i) {
    int fo = fo0 + i * 4;
    int f = f0 + fo;
    int k = which ? f : ((f & 63) * NH + (f >> 6));  // x: k = v*H + u
    dst[((size_t)b * NS + k) * NC + c0 + co] = __float2bfloat16(tile[fo][co]);
  }
}

// ---------------------------------------------------------------------------
// Staging: CPW 1-KB chunks per wave; linear LDS dest, inverse-swizzled global
// source (verified round-1 pattern). Read side uses granule g ^ (row&7).
// ---------------------------------------------------------------------------
template <int CPW>
__device__ __forceinline__ void stage_tile(const char* gsrc, char* ldst,
                                           int wid, int lane) {
  const int lr = lane >> 4, lg = lane & 15;
#pragma unroll
  for (int i = 0; i < CPW; ++i) {
    int c = wid * CPW + i;
    int row = c * 4 + lr;
    int g = lg ^ (row & 7);
    __builtin_amdgcn_global_load_lds(
        (const GLOBAL_AS unsigned*)(gsrc + row * 256 + g * 16),
        (LDS_AS unsigned*)(ldst + c * 1024), 16, 0, 0);
  }
}

// ---------------------------------------------------------------------------
// Pass 1: persistent-column, properly pipelined.
// Grid 768 = 8 b x 24 nt x 4 mq; block 512 (8 waves as 2x4 of 64x32).
// LDS: A dbuf 2x32K + B 32K = 96 KB -> 1 block/CU -> 3 exact rounds of 256.
// Per iter: issue next A-stage FIRST, compute current, then ONE
// vmcnt(0)+s_barrier (stage latency hides under 128 MFMAs).
// Emits part[mq][b][n] = sum over this quarter's 768 m of relu(T)^2.
// ---------------------------------------------------------------------------
__device__ __forceinline__ void gemm_acc(const char* As, const char* Bs,
                                         float cs[2], int wm, int wn, int l15,
                                         int kg) {
  f32x4 acc[4][2] = {};
  const int rx = l15 & 7;
#pragma unroll
  for (int kk = 0; kk < 4; ++kk) {
    int g = (kk * 4 + kg) ^ rx;
    bf16x8 a[4], bb[2];
#pragma unroll
    for (int mi = 0; mi < 4; ++mi)
      a[mi] = *(const bf16x8*)(As + (wm * 64 + mi * 16 + l15) * 256 + g * 16);
#pragma unroll
    for (int ni = 0; ni < 2; ++ni)
      bb[ni] = *(const bf16x8*)(Bs + (wn * 32 + ni * 16 + l15) * 256 + g * 16);
#pragma unroll
    for (int mi = 0; mi < 4; ++mi)
#pragma unroll
      for (int ni = 0; ni < 2; ++ni)
        acc[mi][ni] = __builtin_amdgcn_mfma_f32_16x16x32_bf16(
            a[mi], bb[ni], acc[mi][ni], 0, 0, 0);
  }
#pragma unroll
  for (int ni = 0; ni < 2; ++ni)
#pragma unroll
    for (int mi = 0; mi < 4; ++mi)
#pragma unroll
      for (int r = 0; r < 4; ++r) {
        float v = fmaxf(acc[mi][ni][r], 0.f);
        cs[ni] += v * v;
      }
}

__global__ __launch_bounds__(512, 1) void corr_part_p(
    const __hip_bfloat16* __restrict__ AT,
    const __hip_bfloat16* __restrict__ BT, float* __restrict__ part) {
  __shared__ char smem[98304];  // A0 32K | A1 32K | B 32K
  char* Bs = smem + 65536;
  const int id = blockIdx.x;  // 0..767
  const int b = id & 7;       // XCD pin
  const int tl = id >> 3;     // 0..95
  const int nt = tl >> 2, mq = tl & 3;
  const int t = threadIdx.x;
  const int lane = t & 63, wid = t >> 6;  // 8 waves
  const int wm = wid >> 2, wn = wid & 3;  // 2 x 4 -> 64 x 32 each
  const int l15 = lane & 15, kg = lane >> 4;

  const char* Ab = (const char*)(AT + ((size_t)b * NS + mq * 768) * NC);
  const char* Bg = (const char*)(BT + ((size_t)b * NS + nt * 128) * NC);

  stage_tile<4>(Bg, Bs, wid, lane);
  stage_tile<4>(Ab, smem, wid, lane);  // tile 0 -> buf0
  asm volatile("s_waitcnt vmcnt(0)" ::: "memory");
  __builtin_amdgcn_sched_barrier(0);
  __builtin_amdgcn_s_barrier();

  float cs[2] = {0.f, 0.f};
  int cur = 0;
#pragma unroll 1
  for (int i = 0; i < 6; ++i) {
    if (i + 1 < 6)  // issue next tile's DMA before compute (overlap)
      stage_tile<4>(Ab + (size_t)(i + 1) * 32768, smem + ((cur ^ 1) * 32768),
                    wid, lane);
    gemm_acc(smem + cur * 32768, Bs, cs, wm, wn, l15, kg);
    asm volatile("s_waitcnt vmcnt(0)" ::: "memory");  // next tile landed
    __builtin_amdgcn_sched_barrier(0);
    __builtin_amdgcn_s_barrier();  // all waves past reads of buf[cur]
    cur ^= 1;
  }

  // cross-wave column reduce (verified round-4 math, n=128 span)
#pragma unroll
  for (int ni = 0; ni < 2; ++ni) {
    cs[ni] += __shfl_xor(cs[ni], 16, 64);
    cs[ni] += __shfl_xor(cs[ni], 32, 64);
  }
  float* csum = (float*)smem;  // [2][128]
  if (kg == 0) {
#pragma unroll
    for (int ni = 0; ni < 2; ++ni)
      csum[wm * 128 + wn * 32 + ni * 16 + l15] = cs[ni];
  }
  __syncthreads();
  if (t < 128) {
    float s = csum[t] + csum[128 + t];
    part[(size_t)mq * (NB * NS) + (size_t)b * NS + nt * 128 + t] = s;
  }
}

// ---------------------------------------------------------------------------
// Pass 2 (round-3 verified kernel): 128x128, repack-through-LDS epilogue,
// full-line dwordx4 nontemporal stores. Fused rn now reads 4 partials.
// ---------------------------------------------------------------------------
__global__ __launch_bounds__(256, 2) void corr_out(
    const __hip_bfloat16* __restrict__ AT,
    const __hip_bfloat16* __restrict__ BT, const float* __restrict__ part_in,
    float* __restrict__ out) {
  __shared__ char smem[66560];  // A 32K | B 32K | rn 512 B
  float* rnc = (float*)(smem + 65536);
  const int id = blockIdx.x;
  const int b = id & 7;
  const int tl = id >> 3;
  const int mt = tl / 24, nt = tl - mt * 24;
  const int t = threadIdx.x;
  const int lane = t & 63, wid = t >> 6;
  const int wm = wid >> 1, wn = wid & 1;
  const int l15 = lane & 15, kg = lane >> 4;

  const char* Ag = (const char*)(AT + ((size_t)b * NS + mt * 128) * NC);
  const char* Bg = (const char*)(BT + ((size_t)b * NS + nt * 128) * NC);
  stage_tile<8>(Ag, smem, wid, lane);
  stage_tile<8>(Bg, smem + 32768, wid, lane);
  if (t < 128) {
    float s = 0.f;
#pragma unroll
    for (int q = 0; q < 4; ++q)
      s += part_in[(size_t)q * (NB * NS) + (size_t)b * NS + nt * 128 + t];
    rnc[t] = rsqrtf(s + EPSF);
  }
  __syncthreads();

  f32x4 acc[4][4] = {};
  const int rx = l15 & 7;
#pragma unroll
  for (int kk = 0; kk < 4; ++kk) {
    int g = (kk * 4 + kg) ^ rx;
    bf16x8 a[4], bb[4];
#pragma unroll
    for (int mi = 0; mi < 4; ++mi)
      a[mi] = *(const bf16x8*)(smem + (wm * 64 + mi * 16 + l15) * 256 + g * 16);
#pragma unroll
    for (int ni = 0; ni < 4; ++ni)
      bb[ni] = *(const bf16x8*)(smem + 32768 +
                                (wn * 64 + ni * 16 + l15) * 256 + g * 16);
#pragma unroll
    for (int mi = 0; mi < 4; ++mi)
#pragma unroll
      for (int ni = 0; ni < 4; ++ni)
        acc[mi][ni] = __builtin_amdgcn_mfma_f32_16x16x32_bf16(
            a[mi], bb[ni], acc[mi][ni], 0, 0, 0);
  }

  float rnv[4];
#pragma unroll
  for (int ni = 0; ni < 4; ++ni) rnv[ni] = rnc[wn * 64 + ni * 16 + l15];
  __syncthreads();  // tiles + rnc fully consumed

  float* tf = (float*)smem;  // [128][129]
#pragma unroll
  for (int mi = 0; mi < 4; ++mi)
#pragma unroll
    for (int ni = 0; ni < 4; ++ni)
#pragma unroll
      for (int r = 0; r < 4; ++r) {
        int row = wm * 64 + mi * 16 + kg * 4 + r;
        int col = wn * 64 + ni * 16 + l15;
        tf[row * 129 + col] = fmaxf(acc[mi][ni][r], 0.f) * rnv[ni];
      }
  __syncthreads();

  float* ob = out + (size_t)b * NS * NS + (size_t)(mt * 128) * NS + nt * 128;
  const int rsub = t >> 5, c4 = (t & 31) * 4;
#pragma unroll
  for (int it = 0; it < 16; ++it) {
    int row = it * 8 + rsub;
    f32x4 v = *(const f32x4*)&tf[row * 129 + c4];
    __builtin_nontemporal_store(v, (f32x4*)&ob[(size_t)row * NS + c4]);
  }
}

extern "C" void kernel_launch(void* const* d_in, const int* in_sizes, int n_in,
                              void* d_out, int out_size, void* d_ws,
                              size_t ws_size, hipStream_t stream) {
  const float* x = (const float*)d_in[0];
  const float* y = (const float*)d_in[1];
  float* out = (float*)d_out;
  char* ws = (char*)d_ws;

  const size_t AT_OFF = 0;           // 8*3072*128*2 = 6,291,456
  const size_t BT_OFF = 6291456;     // + 6,291,456
  const size_t PART_OFF = 12582912;  // 4*24576*4 = 393,216
  const size_t NEED = 12976128;
  if (ws_size < NEED) return;

  __hip_bfloat16* AT = (__hip_bfloat16*)(ws + AT_OFF);
  __hip_bfloat16* BT = (__hip_bfloat16*)(ws + BT_OFF);
  float* part = (float*)(ws + PART_OFF);

  transpose_both<<<dim3(3072), dim3(256), 0, stream>>>(x, y, AT, BT);
  corr_part_p<<<dim3(768), dim3(512), 0, stream>>>(AT, BT, part);
  corr_out<<<dim3(4608), dim3(256), 0, stream>>>(AT, BT, part, out);
}